// Round 1
// baseline (3296.914 us; speedup 1.0000x reference)
//
#include <hip/hip_runtime.h>
#include <hip/hip_fp16.h>

typedef unsigned short u16;
typedef unsigned int u32;
using f32x4 = __attribute__((ext_vector_type(4))) float;
using bf16x8 = __attribute__((ext_vector_type(8))) short;

#define M_TOK 4096
#define HID   4096
#define LAT   32768
#define TOPK  64

__device__ __forceinline__ u16 f2bf(float f) {
  u32 u = __builtin_bit_cast(u32, f);
  u32 r = 0x7fffu + ((u >> 16) & 1u);
  return (u16)((u + r) >> 16);
}
__device__ __forceinline__ float bf2f(u16 u) {
  return __builtin_bit_cast(float, (u32)u << 16);
}
__device__ __forceinline__ u16 f2h(float f) {
  _Float16 h = (_Float16)f;
  return __builtin_bit_cast(u16, h);
}
__device__ __forceinline__ float h2f(u16 u) {
  return (float)__builtin_bit_cast(_Float16, u);
}

// K1: xs = bf16(x - pre_bias), stored into x_hat region
__global__ __launch_bounds__(256) void k_xs(const float* __restrict__ x,
                                            const float* __restrict__ pb,
                                            u16* __restrict__ xs) {
  size_t i = ((size_t)blockIdx.x * 256 + threadIdx.x) * 4;
  if (i >= (size_t)M_TOK * HID) return;
  float4 xv = *(const float4*)(x + i);
  float4 bv = *(const float4*)(pb + (i & (HID - 1)));
  ushort4 o;
  o.x = f2bf(xv.x - bv.x); o.y = f2bf(xv.y - bv.y);
  o.z = f2bf(xv.z - bv.z); o.w = f2bf(xv.w - bv.w);
  *(ushort4*)(xs + i) = o;
}

// K2: enc_w fp32 -> bf16 (first half of latents region)
__global__ __launch_bounds__(256) void k_conv(const float* __restrict__ src,
                                              u16* __restrict__ dst, size_t n4) {
  size_t i = (size_t)blockIdx.x * 256 + threadIdx.x;
  size_t stride = (size_t)gridDim.x * 256;
  for (; i < n4; i += stride) {
    float4 v = ((const float4*)src)[i];
    ushort4 o;
    o.x = f2bf(v.x); o.y = f2bf(v.y); o.z = f2bf(v.z); o.w = f2bf(v.w);
    ((ushort4*)dst)[i] = o;
  }
}

// K3: approx pre_acts = xs @ enc_b^T + latent_bias  -> fp16 [M_TOK][LAT]
// m97-style 128x128 tile, BK=32, 4 waves, global_load_lds width 16.
__global__ __launch_bounds__(256) void k_gemm(const u16* __restrict__ A,   // xs bf16 [M_TOK][HID]
                                              const u16* __restrict__ B,   // enc bf16 [LAT][HID]
                                              const float* __restrict__ lbias,
                                              u16* __restrict__ out) {     // fp16 [M_TOK][LAT]
  __shared__ __align__(16) u16 As[128 * 32];
  __shared__ __align__(16) u16 Bs[128 * 32];
  const int tid = threadIdx.x;
  const int lane = tid & 63;
  const int wave = tid >> 6;
  // block order: bm varies fastest (B-panel reuse in L2, A stays L3-resident);
  // XCD swizzle so each XCD owns a contiguous bn range.
  int bid = blockIdx.x;
  int swz = (bid & 7) * 1024 + (bid >> 3);
  const int bm = (swz & 31) * 128;
  const int bn = (swz >> 5) * 128;
  const int wr = wave >> 1, wc = wave & 1;
  f32x4 acc[4][4] = {};

  for (int k0 = 0; k0 < HID; k0 += 32) {
#pragma unroll
    for (int i = 0; i < 2; ++i) {
      int s = i * 256 + tid;
      int r = s >> 2, c = (s & 3) * 8;
      __builtin_amdgcn_global_load_lds(
          (const __attribute__((address_space(1))) void*)(A + (size_t)(bm + r) * HID + k0 + c),
          (__attribute__((address_space(3))) void*)(As + s * 8), 16, 0, 0);
      __builtin_amdgcn_global_load_lds(
          (const __attribute__((address_space(1))) void*)(B + (size_t)(bn + r) * HID + k0 + c),
          (__attribute__((address_space(3))) void*)(Bs + s * 8), 16, 0, 0);
    }
    __syncthreads();
    bf16x8 a[4], b[4];
#pragma unroll
    for (int m = 0; m < 4; ++m)
      a[m] = *(const bf16x8*)(As + (wr * 64 + m * 16 + (lane & 15)) * 32 + (lane >> 4) * 8);
#pragma unroll
    for (int nn = 0; nn < 4; ++nn)
      b[nn] = *(const bf16x8*)(Bs + (wc * 64 + nn * 16 + (lane & 15)) * 32 + (lane >> 4) * 8);
#pragma unroll
    for (int m = 0; m < 4; ++m)
#pragma unroll
      for (int nn = 0; nn < 4; ++nn)
        acc[m][nn] = __builtin_amdgcn_mfma_f32_16x16x32_bf16(a[m], b[nn], acc[m][nn], 0, 0, 0);
    __syncthreads();
  }
  // epilogue: C/D map col=lane&15, row=(lane>>4)*4+reg  [verified m89/m91]
#pragma unroll
  for (int nn = 0; nn < 4; ++nn) {
    int col = bn + wc * 64 + nn * 16 + (lane & 15);
    float lb = lbias[col];
#pragma unroll
    for (int m = 0; m < 4; ++m) {
      int row = bm + wr * 64 + m * 16 + (lane >> 4) * 4;
#pragma unroll
      for (int j = 0; j < 4; ++j)
        out[(size_t)(row + j) * LAT + col] = f2h(acc[m][nn][j] + lb);
    }
  }
}

// K4: per-row exact top-64 rescue.
__global__ __launch_bounds__(256) void k_topk(
    const u16* __restrict__ approx,   // fp16 [M_TOK][LAT]
    const float* __restrict__ x,      // [M_TOK][HID]
    const float* __restrict__ pb,     // [HID]
    const float* __restrict__ enc_w,  // [LAT][HID] fp32 originals
    const float* __restrict__ lbias,  // [LAT]
    int* __restrict__ oidx, float* __restrict__ oval) {
  const int row = blockIdx.x;
  const int tid = threadIdx.x;
  const int lane = tid & 63, wave = tid >> 6;
  const uint4* ap4 = (const uint4*)(approx + (size_t)row * LAT);

  __shared__ int s_cnt, s_n, cnum, innum, selnum;
  __shared__ float s_m;
  __shared__ int lidx[1024];
  __shared__ float laf[1024];
  __shared__ int cidx[352];
  __shared__ double cref[352];
  __shared__ int fidx[64];
  __shared__ float fval[64];

  // pick T0 with 64 <= count(approx >= T0) <= 1000 (first iter succeeds on this data)
  float T0 = 2.25f;
  for (int it = 0; it < 24; ++it) {
    if (tid == 0) s_cnt = 0;
    __syncthreads();
    int c = 0;
    for (int i = tid; i < LAT / 8; i += 256) {
      uint4 v = ap4[i];
      u32 w[4] = {v.x, v.y, v.z, v.w};
#pragma unroll
      for (int q = 0; q < 4; ++q) {
        c += (h2f((u16)(w[q] & 0xffffu)) >= T0);
        c += (h2f((u16)(w[q] >> 16)) >= T0);
      }
    }
    atomicAdd(&s_cnt, c);
    __syncthreads();
    int nc = s_cnt;
    __syncthreads();
    if (nc >= 64 && nc <= 1000) break;
    T0 += (nc < 64) ? -0.25f : 0.25f;
  }

  // collect candidate list
  if (tid == 0) s_n = 0;
  __syncthreads();
  for (int i = tid; i < LAT / 8; i += 256) {
    uint4 v = ap4[i];
    u32 w[4] = {v.x, v.y, v.z, v.w};
#pragma unroll
    for (int q = 0; q < 4; ++q) {
#pragma unroll
      for (int hh = 0; hh < 2; ++hh) {
        u16 raw = hh ? (u16)(w[q] >> 16) : (u16)(w[q] & 0xffffu);
        float a = h2f(raw);
        if (a >= T0) {
          int p = atomicAdd(&s_n, 1);
          if (p < 1024) { lidx[p] = i * 8 + q * 2 + hh; laf[p] = a; }
        }
      }
    }
  }
  __syncthreads();
  int n = min(s_n, 1024);

  // m~ = 64th largest approx value (rank 63 under (value desc, idx asc))
  for (int j = tid; j < n; j += 256) {
    float aj = laf[j]; int ij = lidx[j];
    int rank = 0;
    for (int i2 = 0; i2 < n; ++i2) {
      float ai = laf[i2];
      rank += (ai > aj) || (ai == aj && lidx[i2] < ij);
    }
    if (rank == 63) s_m = aj;
  }
  __syncthreads();
  float mf = s_m;

  // classify: certain-in (> mf+W), uncertain (|a-mf|<=W)
  const float W = 0.0625f;
  if (tid == 0) { cnum = 0; innum = 0; }
  __syncthreads();
  for (int j = tid; j < n; j += 256) {
    float a = laf[j];
    if (a > mf + W) {
      int p = atomicAdd(&innum, 1);
      fidx[p] = lidx[j]; fval[p] = a;       // p <= 62 guaranteed
    } else if (a >= mf - W) {
      int p = atomicAdd(&cnum, 1);
      if (p < 352) cidx[p] = lidx[j];
    }
  }
  __syncthreads();
  int nin = innum;
  int nu = min(cnum, 352);

  // fp64 exact refinement of uncertain band (one wave per candidate)
  const float* xrow = x + (size_t)row * HID;
  for (int cc = wave; cc < nu; cc += 4) {
    const float* wrow = enc_w + (size_t)cidx[cc] * HID;
    double s = 0.0;
    for (int i = lane * 4; i < HID; i += 256) {
      float4 wv = *(const float4*)(wrow + i);
      float4 xv = *(const float4*)(xrow + i);
      float4 bv = *(const float4*)(pb + i);
      s += ((double)xv.x - (double)bv.x) * (double)wv.x;
      s += ((double)xv.y - (double)bv.y) * (double)wv.y;
      s += ((double)xv.z - (double)bv.z) * (double)wv.z;
      s += ((double)xv.w - (double)bv.w) * (double)wv.w;
    }
#pragma unroll
    for (int off = 32; off > 0; off >>= 1) s += __shfl_down(s, off);
    if (lane == 0) cref[cc] = s + (double)lbias[cidx[cc]];
  }
  __syncthreads();

  // select top (64 - nin) uncertain by refined value
  int need = 64 - nin;
  if (tid == 0) selnum = 0;
  __syncthreads();
  for (int j = tid; j < nu; j += 256) {
    double rj = cref[j]; int ij = cidx[j];
    int rank = 0;
    for (int i2 = 0; i2 < nu; ++i2) {
      double ri = cref[i2];
      rank += (ri > rj) || (ri == rj && cidx[i2] < ij);
    }
    if (rank < need) {
      int p = atomicAdd(&selnum, 1);
      fidx[nin + p] = ij; fval[nin + p] = (float)rj;
    }
  }
  __syncthreads();

  // deterministic output: sort 64 by index
  if (tid < 64) {
    int my = fidx[tid]; float v = fval[tid];
    int rank = 0;
#pragma unroll
    for (int i2 = 0; i2 < 64; ++i2) rank += (fidx[i2] < my);
    oidx[row * 64 + rank] = my;
    oval[row * 64 + rank] = v;
  }
}

// K5: dec_w [HID][LAT] fp32 -> decT bf16 [LAT][HID]
__global__ __launch_bounds__(256) void k_trans(const float* __restrict__ dw,
                                               u16* __restrict__ dt) {
  __shared__ float tile[64][65];
  int l0 = blockIdx.x * 64;
  int h0 = blockIdx.y * 64;
  int tx = threadIdx.x & 15;
  int ty = threadIdx.x >> 4;
#pragma unroll
  for (int i = 0; i < 4; ++i) {
    int r = ty + i * 16;
    float4 v = *(const float4*)(dw + (size_t)(h0 + r) * LAT + l0 + tx * 4);
    tile[r][tx * 4 + 0] = v.x; tile[r][tx * 4 + 1] = v.y;
    tile[r][tx * 4 + 2] = v.z; tile[r][tx * 4 + 3] = v.w;
  }
  __syncthreads();
#pragma unroll
  for (int i = 0; i < 4; ++i) {
    int r = ty + i * 16;  // latent index within tile
    ushort4 o;
    o.x = f2bf(tile[tx * 4 + 0][r]);
    o.y = f2bf(tile[tx * 4 + 1][r]);
    o.z = f2bf(tile[tx * 4 + 2][r]);
    o.w = f2bf(tile[tx * 4 + 3][r]);
    *(ushort4*)(dt + (size_t)(l0 + r) * HID + h0 + tx * 4) = o;
  }
}

// K6: x_hat[n][h] = sum_j val_j * decT[idx_j][h] + pre_bias[h]
__global__ __launch_bounds__(256) void k_decode(
    const int* __restrict__ oidx, const float* __restrict__ oval,
    const u16* __restrict__ dt, const float* __restrict__ pb,
    float* __restrict__ xh) {
  const int n = blockIdx.x, tid = threadIdx.x;
  __shared__ int sidx[64];
  __shared__ float sval[64];
  if (tid < 64) { sidx[tid] = oidx[n * 64 + tid]; sval[tid] = oval[n * 64 + tid]; }
  __syncthreads();
  const int h0 = tid * 16;
  float acc[16];
#pragma unroll
  for (int q = 0; q < 4; ++q) {
    float4 b = *(const float4*)(pb + h0 + q * 4);
    acc[q * 4 + 0] = b.x; acc[q * 4 + 1] = b.y;
    acc[q * 4 + 2] = b.z; acc[q * 4 + 3] = b.w;
  }
  for (int j = 0; j < 64; ++j) {
    float v = sval[j];
    const uint4* w = (const uint4*)(dt + (size_t)sidx[j] * HID + h0);
    uint4 p0 = w[0], p1 = w[1];
    u32 u[8] = {p0.x, p0.y, p0.z, p0.w, p1.x, p1.y, p1.z, p1.w};
#pragma unroll
    for (int q = 0; q < 8; ++q) {
      float lo = __builtin_bit_cast(float, u[q] << 16);
      float hi = __builtin_bit_cast(float, u[q] & 0xffff0000u);
      acc[q * 2 + 0] = fmaf(v, lo, acc[q * 2 + 0]);
      acc[q * 2 + 1] = fmaf(v, hi, acc[q * 2 + 1]);
    }
  }
#pragma unroll
  for (int q = 0; q < 4; ++q) {
    float4 o;
    o.x = acc[q * 4 + 0]; o.y = acc[q * 4 + 1];
    o.z = acc[q * 4 + 2]; o.w = acc[q * 4 + 3];
    *(float4*)(xh + (size_t)n * HID + h0 + q * 4) = o;
  }
}

// K7: zero latents
__global__ __launch_bounds__(256) void k_zero(float4* __restrict__ p, size_t n4) {
  size_t i = (size_t)blockIdx.x * 256 + threadIdx.x;
  size_t stride = (size_t)gridDim.x * 256;
  float4 z = {0.f, 0.f, 0.f, 0.f};
  for (; i < n4; i += stride) p[i] = z;
}

// K8: scatter top-k values
__global__ __launch_bounds__(256) void k_scatter(const int* __restrict__ oidx,
                                                 const float* __restrict__ oval,
                                                 float* __restrict__ lat) {
  int t = blockIdx.x * 256 + threadIdx.x;
  if (t >= M_TOK * TOPK) return;
  int r = t >> 6;
  lat[(size_t)r * LAT + oidx[t]] = oval[t];
}

extern "C" void kernel_launch(void* const* d_in, const int* in_sizes, int n_in,
                              void* d_out, int out_size, void* d_ws, size_t ws_size,
                              hipStream_t stream) {
  const float* x = (const float*)d_in[0];
  const float* pre_bias = (const float*)d_in[1];
  const float* latent_bias = (const float*)d_in[2];
  const float* enc_w = (const float*)d_in[3];
  const float* dec_w = (const float*)d_in[4];

  float* latents = (float*)d_out;
  float* xhat = latents + (size_t)M_TOK * LAT;

  // scratch carved from d_out regions (all dead before final writes):
  u16* xs = (u16*)xhat;                                            // bf16 [M_TOK][HID], 33.5MB of x_hat region
  u16* encb = (u16*)latents;                                       // bf16 [LAT][HID], first 268MB of latents region
  u16* approx = (u16*)((char*)d_out + (size_t)M_TOK * LAT * 2);    // fp16 [M_TOK][LAT], second 268MB
  u16* decT = (u16*)latents;                                       // bf16 [LAT][HID], reuses first half after topk
  int* oidx = (int*)d_ws;                                          // [M_TOK][64]
  float* oval = (float*)((char*)d_ws + (size_t)M_TOK * TOPK * 4);  // [M_TOK][64]

  k_xs<<<(M_TOK * HID / 4 + 255) / 256, 256, 0, stream>>>(x, pre_bias, xs);
  k_conv<<<4096, 256, 0, stream>>>(enc_w, encb, (size_t)LAT * HID / 4);
  k_gemm<<<(LAT / 128) * (M_TOK / 128), 256, 0, stream>>>(xs, encb, latent_bias, approx);
  k_topk<<<M_TOK, 256, 0, stream>>>(approx, x, pre_bias, enc_w, latent_bias, oidx, oval);
  k_trans<<<dim3(LAT / 64, HID / 64), 256, 0, stream>>>(dec_w, decT);
  k_decode<<<M_TOK, 256, 0, stream>>>(oidx, oval, decT, pre_bias, xhat);
  k_zero<<<2048, 256, 0, stream>>>((float4*)latents, (size_t)M_TOK * LAT / 4);
  k_scatter<<<(M_TOK * TOPK + 255) / 256, 256, 0, stream>>>(oidx, oval, latents);
}

// Round 2
// 2538.272 us; speedup vs baseline: 1.2989x; 1.2989x over previous
//
#include <hip/hip_runtime.h>
#include <hip/hip_fp16.h>

typedef unsigned short u16;
typedef unsigned int u32;
using f32x4 = __attribute__((ext_vector_type(4))) float;
using bf16x8 = __attribute__((ext_vector_type(8))) short;

#define M_TOK 4096
#define HID   4096
#define LAT   32768
#define TOPK  64

#define BM 256
#define BN 256
#define BK 64
#define NT (HID / BK)   // 64 K-tiles

__device__ __forceinline__ u16 f2bf(float f) {
  u32 u = __builtin_bit_cast(u32, f);
  u32 r = 0x7fffu + ((u >> 16) & 1u);
  return (u16)((u + r) >> 16);
}
__device__ __forceinline__ u16 f2h(float f) {
  _Float16 h = (_Float16)f;
  return __builtin_bit_cast(u16, h);
}
__device__ __forceinline__ float h2f(u16 u) {
  return (float)__builtin_bit_cast(_Float16, u);
}

// K1: xs = bf16(x - pre_bias), stored into x_hat region
__global__ __launch_bounds__(256) void k_xs(const float* __restrict__ x,
                                            const float* __restrict__ pb,
                                            u16* __restrict__ xs) {
  size_t i = ((size_t)blockIdx.x * 256 + threadIdx.x) * 4;
  if (i >= (size_t)M_TOK * HID) return;
  float4 xv = *(const float4*)(x + i);
  float4 bv = *(const float4*)(pb + (i & (HID - 1)));
  ushort4 o;
  o.x = f2bf(xv.x - bv.x); o.y = f2bf(xv.y - bv.y);
  o.z = f2bf(xv.z - bv.z); o.w = f2bf(xv.w - bv.w);
  *(ushort4*)(xs + i) = o;
}

// K2: enc_w fp32 -> bf16
__global__ __launch_bounds__(256) void k_conv(const float* __restrict__ src,
                                              u16* __restrict__ dst, size_t n4) {
  size_t i = (size_t)blockIdx.x * 256 + threadIdx.x;
  size_t stride = (size_t)gridDim.x * 256;
  for (; i < n4; i += stride) {
    float4 v = ((const float4*)src)[i];
    ushort4 o;
    o.x = f2bf(v.x); o.y = f2bf(v.y); o.z = f2bf(v.z); o.w = f2bf(v.w);
    ((ushort4*)dst)[i] = o;
  }
}

// K3: approx pre_acts = xs @ enc_b^T + latent_bias -> fp16 [M_TOK][LAT]
// 256x256 8-phase template (T2 swizzle + T3/T4 counted vmcnt + T5 setprio).
__global__ __launch_bounds__(512, 2) void k_gemm(const u16* __restrict__ A,   // bf16 [M_TOK][HID]
                                                 const u16* __restrict__ B,   // bf16 [LAT][HID]
                                                 const float* __restrict__ lbias,
                                                 u16* __restrict__ out) {     // fp16 [M_TOK][LAT]
  // [dbuf][half][row][col] ; half-tile = 128x64 bf16 = 16 KB
  __shared__ __align__(16) u16 Asm[2][2][128][64];
  __shared__ __align__(16) u16 Bsm[2][2][128][64];
  const int tid = threadIdx.x;
  const int lane = tid & 63;
  const int wave = tid >> 6;
  const int wm = wave >> 2;   // 0..1
  const int wn = wave & 3;    // 0..3

  // bijective XCD swizzle: nwg=2048, 8 XCDs, 256 blocks each; bm fastest within XCD
  const int bid = blockIdx.x;
  const int wg = (bid & 7) * 256 + (bid >> 3);
  const int bm = (wg & 15) * BM;
  const int bn = (wg >> 4) * BN;

  // ---- staging: global_load_lds (linear LDS dest) + inverse-swizzled global src
  // LDS phys layout per half-tile: [pr][s*8 elems]; logical col = (s ^ (pr&7))*8
  auto stageA = [&](int kt, int h) {
#pragma unroll
    for (int q = 0; q < 2; ++q) {
      int idx = q * 512 + tid;
      int pr = idx >> 3, s = idx & 7;
      int lcol = (s ^ (pr & 7)) << 3;
      __builtin_amdgcn_global_load_lds(
          (const __attribute__((address_space(1))) void*)(
              A + (size_t)(bm + h * 128 + pr) * HID + kt * BK + lcol),
          (__attribute__((address_space(3))) void*)(&Asm[kt & 1][h][pr][s << 3]),
          16, 0, 0);
    }
  };
  auto stageB = [&](int kt, int h) {
#pragma unroll
    for (int q = 0; q < 2; ++q) {
      int idx = q * 512 + tid;
      int pr = idx >> 3, s = idx & 7;
      int lcol = (s ^ (pr & 7)) << 3;
      __builtin_amdgcn_global_load_lds(
          (const __attribute__((address_space(1))) void*)(
              B + (size_t)(bn + h * 128 + pr) * HID + kt * BK + lcol),
          (__attribute__((address_space(3))) void*)(&Bsm[kt & 1][h][pr][s << 3]),
          16, 0, 0);
    }
  };
  // ---- swizzled fragment reads (ds_read_b128, conflict-free)
  auto readA = [&](int cur, int m, int ks) -> bf16x8 {
    int pr = m * 16 + (lane & 15);
    int pe = (ks * 32 + ((lane >> 4) << 3)) ^ ((pr & 7) << 3);
    return *(const bf16x8*)(&Asm[cur][wm][pr][pe]);
  };
  auto readB = [&](int cur, int n, int ks) -> bf16x8 {
    int pr = (wn & 1) * 64 + n * 16 + (lane & 15);
    int pe = (ks * 32 + ((lane >> 4) << 3)) ^ ((pr & 7) << 3);
    return *(const bf16x8*)(&Bsm[cur][wn >> 1][pr][pe]);
  };

  f32x4 acc[8][4] = {};
  bf16x8 a[4][2], b[4][2];

  // prologue: K-tile 0 fully + B halves of K-tile 1 (loop issues A(kt+1), B(kt+2))
  stageA(0, 0); stageA(0, 1); stageB(0, 0); stageB(0, 1);
  stageB(1, 0); stageB(1, 1);
  asm volatile("s_waitcnt vmcnt(4)" ::: "memory");
  __builtin_amdgcn_s_barrier();

#pragma unroll 1
  for (int kt = 0; kt < NT; ++kt) {
    const int cur = kt & 1;
    // ---- P1: read A m0-3 + B n0-1 ; stage A-half0(kt+1) ; MFMA m0-3 x n0-1
#pragma unroll
    for (int m = 0; m < 4; ++m)
#pragma unroll
      for (int ks = 0; ks < 2; ++ks) a[m][ks] = readA(cur, m, ks);
#pragma unroll
    for (int n = 0; n < 2; ++n)
#pragma unroll
      for (int ks = 0; ks < 2; ++ks) b[n][ks] = readB(cur, n, ks);
    if (kt + 1 < NT) stageA(kt + 1, 0);
    __builtin_amdgcn_s_barrier();
    asm volatile("s_waitcnt lgkmcnt(0)" ::: "memory");
    __builtin_amdgcn_s_setprio(1);
#pragma unroll
    for (int ks = 0; ks < 2; ++ks)
#pragma unroll
      for (int m = 0; m < 4; ++m)
#pragma unroll
        for (int n = 0; n < 2; ++n)
          acc[m][n] = __builtin_amdgcn_mfma_f32_16x16x32_bf16(a[m][ks], b[n][ks], acc[m][n], 0, 0, 0);
    __builtin_amdgcn_s_setprio(0);
    __builtin_amdgcn_s_barrier();
    // ---- P2: read B n2-3 ; stage A-half1(kt+1) ; MFMA m0-3 x n2-3
#pragma unroll
    for (int n = 2; n < 4; ++n)
#pragma unroll
      for (int ks = 0; ks < 2; ++ks) b[n][ks] = readB(cur, n, ks);
    if (kt + 1 < NT) stageA(kt + 1, 1);
    __builtin_amdgcn_s_barrier();
    asm volatile("s_waitcnt lgkmcnt(0)" ::: "memory");
    __builtin_amdgcn_s_setprio(1);
#pragma unroll
    for (int ks = 0; ks < 2; ++ks)
#pragma unroll
      for (int m = 0; m < 4; ++m)
#pragma unroll
        for (int n = 2; n < 4; ++n)
          acc[m][n] = __builtin_amdgcn_mfma_f32_16x16x32_bf16(a[m][ks], b[n][ks], acc[m][n], 0, 0, 0);
    __builtin_amdgcn_s_setprio(0);
    __builtin_amdgcn_s_barrier();
    // ---- P3: read A m4-7 ; stage B-half0(kt+2) ; MFMA m4-7 x n2-3
#pragma unroll
    for (int m = 0; m < 4; ++m)
#pragma unroll
      for (int ks = 0; ks < 2; ++ks) a[m][ks] = readA(cur, m + 4, ks);
    if (kt + 2 < NT) stageB(kt + 2, 0);
    __builtin_amdgcn_s_barrier();
    asm volatile("s_waitcnt lgkmcnt(0)" ::: "memory");
    __builtin_amdgcn_s_setprio(1);
#pragma unroll
    for (int ks = 0; ks < 2; ++ks)
#pragma unroll
      for (int m = 0; m < 4; ++m)
#pragma unroll
        for (int n = 2; n < 4; ++n)
          acc[m + 4][n] = __builtin_amdgcn_mfma_f32_16x16x32_bf16(a[m][ks], b[n][ks], acc[m + 4][n], 0, 0, 0);
    __builtin_amdgcn_s_setprio(0);
    __builtin_amdgcn_s_barrier();
    // ---- P4: stage B-half1(kt+2) ; counted vmcnt ; MFMA m4-7 x n0-1
    if (kt + 2 < NT) {
      stageB(kt + 2, 1);
      asm volatile("s_waitcnt vmcnt(4)" ::: "memory");
    } else {
      asm volatile("s_waitcnt vmcnt(0)" ::: "memory");
    }
    __builtin_amdgcn_s_barrier();
    __builtin_amdgcn_s_setprio(1);
#pragma unroll
    for (int ks = 0; ks < 2; ++ks)
#pragma unroll
      for (int m = 0; m < 4; ++m)
#pragma unroll
        for (int n = 0; n < 2; ++n)
          acc[m + 4][n] = __builtin_amdgcn_mfma_f32_16x16x32_bf16(a[m][ks], b[n][ks], acc[m + 4][n], 0, 0, 0);
    __builtin_amdgcn_s_setprio(0);
    __builtin_amdgcn_s_barrier();
  }

  // epilogue: C/D map col=lane&15, row=(lane>>4)*4+j
#pragma unroll
  for (int n = 0; n < 4; ++n) {
    int col = bn + wn * 64 + n * 16 + (lane & 15);
    float lb = lbias[col];
#pragma unroll
    for (int m = 0; m < 8; ++m) {
      int row = bm + wm * 128 + m * 16 + ((lane >> 4) << 2);
#pragma unroll
      for (int j = 0; j < 4; ++j)
        out[(size_t)(row + j) * LAT + col] = f2h(acc[m][n][j] + lb);
    }
  }
}

// K4: per-row exact top-64 rescue.
__global__ __launch_bounds__(256) void k_topk(
    const u16* __restrict__ approx,   // fp16 [M_TOK][LAT]
    const float* __restrict__ x,      // [M_TOK][HID]
    const float* __restrict__ pb,     // [HID]
    const float* __restrict__ enc_w,  // [LAT][HID] fp32 originals
    const float* __restrict__ lbias,  // [LAT]
    int* __restrict__ oidx, float* __restrict__ oval) {
  const int row = blockIdx.x;
  const int tid = threadIdx.x;
  const int lane = tid & 63, wave = tid >> 6;
  const uint4* ap4 = (const uint4*)(approx + (size_t)row * LAT);

  __shared__ int s_cnt, s_n, cnum, innum, selnum;
  __shared__ float s_m;
  __shared__ int lidx[1024];
  __shared__ float laf[1024];
  __shared__ int cidx[352];
  __shared__ double cref[352];
  __shared__ int fidx[64];
  __shared__ float fval[64];

  float T0 = 2.25f;
  for (int it = 0; it < 24; ++it) {
    if (tid == 0) s_cnt = 0;
    __syncthreads();
    int c = 0;
    for (int i = tid; i < LAT / 8; i += 256) {
      uint4 v = ap4[i];
      u32 w[4] = {v.x, v.y, v.z, v.w};
#pragma unroll
      for (int q = 0; q < 4; ++q) {
        c += (h2f((u16)(w[q] & 0xffffu)) >= T0);
        c += (h2f((u16)(w[q] >> 16)) >= T0);
      }
    }
    atomicAdd(&s_cnt, c);
    __syncthreads();
    int nc = s_cnt;
    __syncthreads();
    if (nc >= 64 && nc <= 1000) break;
    T0 += (nc < 64) ? -0.25f : 0.25f;
  }

  if (tid == 0) s_n = 0;
  __syncthreads();
  for (int i = tid; i < LAT / 8; i += 256) {
    uint4 v = ap4[i];
    u32 w[4] = {v.x, v.y, v.z, v.w};
#pragma unroll
    for (int q = 0; q < 4; ++q) {
#pragma unroll
      for (int hh = 0; hh < 2; ++hh) {
        u16 raw = hh ? (u16)(w[q] >> 16) : (u16)(w[q] & 0xffffu);
        float aa = h2f(raw);
        if (aa >= T0) {
          int p = atomicAdd(&s_n, 1);
          if (p < 1024) { lidx[p] = i * 8 + q * 2 + hh; laf[p] = aa; }
        }
      }
    }
  }
  __syncthreads();
  int n = min(s_n, 1024);

  for (int j = tid; j < n; j += 256) {
    float aj = laf[j]; int ij = lidx[j];
    int rank = 0;
    for (int i2 = 0; i2 < n; ++i2) {
      float ai = laf[i2];
      rank += (ai > aj) || (ai == aj && lidx[i2] < ij);
    }
    if (rank == 63) s_m = aj;
  }
  __syncthreads();
  float mf = s_m;

  const float W = 0.0625f;
  if (tid == 0) { cnum = 0; innum = 0; }
  __syncthreads();
  for (int j = tid; j < n; j += 256) {
    float aa = laf[j];
    if (aa > mf + W) {
      int p = atomicAdd(&innum, 1);
      fidx[p] = lidx[j]; fval[p] = aa;
    } else if (aa >= mf - W) {
      int p = atomicAdd(&cnum, 1);
      if (p < 352) cidx[p] = lidx[j];
    }
  }
  __syncthreads();
  int nin = innum;
  int nu = min(cnum, 352);

  const float* xrow = x + (size_t)row * HID;
  for (int cc = wave; cc < nu; cc += 4) {
    const float* wrow = enc_w + (size_t)cidx[cc] * HID;
    double s = 0.0;
    for (int i = lane * 4; i < HID; i += 256) {
      float4 wv = *(const float4*)(wrow + i);
      float4 xv = *(const float4*)(xrow + i);
      float4 bv = *(const float4*)(pb + i);
      s += ((double)xv.x - (double)bv.x) * (double)wv.x;
      s += ((double)xv.y - (double)bv.y) * (double)wv.y;
      s += ((double)xv.z - (double)bv.z) * (double)wv.z;
      s += ((double)xv.w - (double)bv.w) * (double)wv.w;
    }
#pragma unroll
    for (int off = 32; off > 0; off >>= 1) s += __shfl_down(s, off);
    if (lane == 0) cref[cc] = s + (double)lbias[cidx[cc]];
  }
  __syncthreads();

  int need = 64 - nin;
  if (tid == 0) selnum = 0;
  __syncthreads();
  for (int j = tid; j < nu; j += 256) {
    double rj = cref[j]; int ij = cidx[j];
    int rank = 0;
    for (int i2 = 0; i2 < nu; ++i2) {
      double ri = cref[i2];
      rank += (ri > rj) || (ri == rj && cidx[i2] < ij);
    }
    if (rank < need) {
      int p = atomicAdd(&selnum, 1);
      fidx[nin + p] = ij; fval[nin + p] = (float)rj;
    }
  }
  __syncthreads();

  if (tid < 64) {
    int my = fidx[tid]; float v = fval[tid];
    int rank = 0;
#pragma unroll
    for (int i2 = 0; i2 < 64; ++i2) rank += (fidx[i2] < my);
    oidx[row * 64 + rank] = my;
    oval[row * 64 + rank] = v;
  }
}

// K5: dec_w [HID][LAT] fp32 -> decT bf16 [LAT][HID]
__global__ __launch_bounds__(256) void k_trans(const float* __restrict__ dw,
                                               u16* __restrict__ dt) {
  __shared__ float tile[64][65];
  int l0 = blockIdx.x * 64;
  int h0 = blockIdx.y * 64;
  int tx = threadIdx.x & 15;
  int ty = threadIdx.x >> 4;
#pragma unroll
  for (int i = 0; i < 4; ++i) {
    int r = ty + i * 16;
    float4 v = *(const float4*)(dw + (size_t)(h0 + r) * LAT + l0 + tx * 4);
    tile[r][tx * 4 + 0] = v.x; tile[r][tx * 4 + 1] = v.y;
    tile[r][tx * 4 + 2] = v.z; tile[r][tx * 4 + 3] = v.w;
  }
  __syncthreads();
#pragma unroll
  for (int i = 0; i < 4; ++i) {
    int r = ty + i * 16;
    ushort4 o;
    o.x = f2bf(tile[tx * 4 + 0][r]);
    o.y = f2bf(tile[tx * 4 + 1][r]);
    o.z = f2bf(tile[tx * 4 + 2][r]);
    o.w = f2bf(tile[tx * 4 + 3][r]);
    *(ushort4*)(dt + (size_t)(l0 + r) * HID + h0 + tx * 4) = o;
  }
}

// K6: x_hat[n][h] = sum_j val_j * decT[idx_j][h] + pre_bias[h]
__global__ __launch_bounds__(256) void k_decode(
    const int* __restrict__ oidx, const float* __restrict__ oval,
    const u16* __restrict__ dt, const float* __restrict__ pb,
    float* __restrict__ xh) {
  const int n = blockIdx.x, tid = threadIdx.x;
  __shared__ int sidx[64];
  __shared__ float sval[64];
  if (tid < 64) { sidx[tid] = oidx[n * 64 + tid]; sval[tid] = oval[n * 64 + tid]; }
  __syncthreads();
  const int h0 = tid * 16;
  float acc[16];
#pragma unroll
  for (int q = 0; q < 4; ++q) {
    float4 b = *(const float4*)(pb + h0 + q * 4);
    acc[q * 4 + 0] = b.x; acc[q * 4 + 1] = b.y;
    acc[q * 4 + 2] = b.z; acc[q * 4 + 3] = b.w;
  }
  for (int j = 0; j < 64; ++j) {
    float v = sval[j];
    const uint4* w = (const uint4*)(dt + (size_t)sidx[j] * HID + h0);
    uint4 p0 = w[0], p1 = w[1];
    u32 u[8] = {p0.x, p0.y, p0.z, p0.w, p1.x, p1.y, p1.z, p1.w};
#pragma unroll
    for (int q = 0; q < 8; ++q) {
      float lo = __builtin_bit_cast(float, u[q] << 16);
      float hi = __builtin_bit_cast(float, u[q] & 0xffff0000u);
      acc[q * 2 + 0] = fmaf(v, lo, acc[q * 2 + 0]);
      acc[q * 2 + 1] = fmaf(v, hi, acc[q * 2 + 1]);
    }
  }
#pragma unroll
  for (int q = 0; q < 4; ++q) {
    float4 o;
    o.x = acc[q * 4 + 0]; o.y = acc[q * 4 + 1];
    o.z = acc[q * 4 + 2]; o.w = acc[q * 4 + 3];
    *(float4*)(xh + (size_t)n * HID + h0 + q * 4) = o;
  }
}

// K7: zero latents
__global__ __launch_bounds__(256) void k_zero(float4* __restrict__ p, size_t n4) {
  size_t i = (size_t)blockIdx.x * 256 + threadIdx.x;
  size_t stride = (size_t)gridDim.x * 256;
  float4 z = {0.f, 0.f, 0.f, 0.f};
  for (; i < n4; i += stride) p[i] = z;
}

// K8: scatter top-k values
__global__ __launch_bounds__(256) void k_scatter(const int* __restrict__ oidx,
                                                 const float* __restrict__ oval,
                                                 float* __restrict__ lat) {
  int t = blockIdx.x * 256 + threadIdx.x;
  if (t >= M_TOK * TOPK) return;
  int r = t >> 6;
  lat[(size_t)r * LAT + oidx[t]] = oval[t];
}

extern "C" void kernel_launch(void* const* d_in, const int* in_sizes, int n_in,
                              void* d_out, int out_size, void* d_ws, size_t ws_size,
                              hipStream_t stream) {
  const float* x = (const float*)d_in[0];
  const float* pre_bias = (const float*)d_in[1];
  const float* latent_bias = (const float*)d_in[2];
  const float* enc_w = (const float*)d_in[3];
  const float* dec_w = (const float*)d_in[4];

  float* latents = (float*)d_out;
  float* xhat = latents + (size_t)M_TOK * LAT;

  u16* xs = (u16*)xhat;                                            // bf16 [M_TOK][HID]
  u16* encb = (u16*)latents;                                       // bf16 [LAT][HID]
  u16* approx = (u16*)((char*)d_out + (size_t)M_TOK * LAT * 2);    // fp16 [M_TOK][LAT]
  u16* decT = (u16*)latents;                                       // bf16 [LAT][HID]
  int* oidx = (int*)d_ws;
  float* oval = (float*)((char*)d_ws + (size_t)M_TOK * TOPK * 4);

  k_xs<<<(M_TOK * HID / 4 + 255) / 256, 256, 0, stream>>>(x, pre_bias, xs);
  k_conv<<<4096, 256, 0, stream>>>(enc_w, encb, (size_t)LAT * HID / 4);
  k_gemm<<<(LAT / BN) * (M_TOK / BM), 512, 0, stream>>>(xs, encb, latent_bias, approx);
  k_topk<<<M_TOK, 256, 0, stream>>>(approx, x, pre_bias, enc_w, latent_bias, oidx, oval);
  k_trans<<<dim3(LAT / 64, HID / 64), 256, 0, stream>>>(dec_w, decT);
  k_decode<<<M_TOK, 256, 0, stream>>>(oidx, oval, decT, pre_bias, xhat);
  k_zero<<<2048, 256, 0, stream>>>((float4*)latents, (size_t)M_TOK * LAT / 4);
  k_scatter<<<(M_TOK * TOPK + 255) / 256, 256, 0, stream>>>(oidx, oval, latents);
}